// Round 2
// baseline (1090.666 us; speedup 1.0000x reference)
//
#include <hip/hip_runtime.h>
#include <hip/hip_bf16.h>
#include <stdint.h>
#include <stddef.h>

typedef __attribute__((ext_vector_type(8))) __bf16 bf16x8;
typedef __attribute__((ext_vector_type(4))) float f32x4;

#define MFMA16(a, b, c) __builtin_amdgcn_mfma_f32_16x16x32_bf16((a), (b), (c), 0, 0, 0)

static constexpr int Bc = 4, Nc = 4096, Dc = 1024, Hc = 16, HDc = 64;

__device__ __forceinline__ uint16_t f2bf(float f) {
  __bf16 h = (__bf16)f;
  return __builtin_bit_cast(uint16_t, h);
}

// async global->LDS, 16B per lane. LDS dest must be wave-uniform-base + lane*16.
__device__ __forceinline__ void gload16(const void* g, void* l) {
  __builtin_amdgcn_global_load_lds(
      (__attribute__((address_space(1))) void*)(g),
      (__attribute__((address_space(3))) void*)(l), 16, 0, 0);
}

// ---------------------------------------------------------------------------
// f32 -> bf16 convert (vectorized, 8 elems/thread). n must be a multiple of 8.
// ---------------------------------------------------------------------------
__global__ __launch_bounds__(256) void cvt_f32_bf16(
    const float* __restrict__ src, uint16_t* __restrict__ dst, int n) {
  const int i = (blockIdx.x * 256 + threadIdx.x) * 8;
  if (i >= n) return;
  const float4 a = *(const float4*)(src + i);
  const float4 b = *(const float4*)(src + i + 4);
  union { uint16_t u[8]; uint4 v; } o;
  o.u[0] = f2bf(a.x); o.u[1] = f2bf(a.y); o.u[2] = f2bf(a.z); o.u[3] = f2bf(a.w);
  o.u[4] = f2bf(b.x); o.u[5] = f2bf(b.y); o.u[6] = f2bf(b.z); o.u[7] = f2bf(b.w);
  *(uint4*)(dst + i) = o.v;
}

// ---------------------------------------------------------------------------
// BT-GEMM: C[m, e] = sum_k A[m, k] * Bw[e, k].  128x128 tile, BK=64, 4 waves.
// EPI=0: QKV projection epilogue -> RoPE (f32 rot) -> Q/K [B,H,N,HD] bf16,
//        V transposed [B,H,HD,N] bf16
// EPI=1: bias add (f32) -> Out [M, 1024] f32
// ---------------------------------------------------------------------------
template <int EPI>
__global__ __launch_bounds__(256, 2) void gemm_bt(
    const uint16_t* __restrict__ A, const uint16_t* __restrict__ Bw, int K,
    const float* __restrict__ rot, uint16_t* __restrict__ Qb,
    uint16_t* __restrict__ Kb, uint16_t* __restrict__ Vg,
    const float* __restrict__ bias, float* __restrict__ Out) {
  __shared__ __align__(16) uint16_t As[128 * 64];
  __shared__ __align__(16) uint16_t Bs[128 * 64];
  const int tid = threadIdx.x;
  const int lane = tid & 63, wave = tid >> 6;
  const int l15 = lane & 15, g = lane >> 4;
  const int wr = wave >> 1, wc = wave & 1;
  const int m0 = blockIdx.y * 128;
  const int n0 = blockIdx.x * 128;

  f32x4 acc[4][4];
  const f32x4 fz = {0.f, 0.f, 0.f, 0.f};
#pragma unroll
  for (int i = 0; i < 4; ++i)
#pragma unroll
    for (int j = 0; j < 4; ++j) acc[i][j] = fz;

  for (int kt = 0; kt < K; kt += 64) {
    __syncthreads();  // previous iter's LDS reads done before overwrite
#pragma unroll
    for (int i = 0; i < 4; ++i) {
      const int chunk = tid + i * 256;  // 0..1023 : 128 rows x 8 chunks(16B)
      const int r = chunk >> 3, c = chunk & 7;
      const int cs = c ^ (r & 7);  // pre-swizzled source (linear LDS dest)
      gload16(A + (size_t)(m0 + r) * K + kt + cs * 8, &As[chunk * 8]);
      gload16(Bw + (size_t)(n0 + r) * K + kt + cs * 8, &Bs[chunk * 8]);
    }
    __syncthreads();  // implies vmcnt(0): staged data visible

    bf16x8 af[4][2], bfr[4][2];
#pragma unroll
    for (int mi = 0; mi < 4; ++mi)
#pragma unroll
      for (int kk = 0; kk < 2; ++kk) {
        const int r = wr * 64 + mi * 16 + l15;
        const int ca = (kk * 4 + g) ^ (r & 7);
        af[mi][kk] = *(const bf16x8*)((const char*)As + r * 128 + ca * 16);
        const int r2 = wc * 64 + mi * 16 + l15;
        const int cb = (kk * 4 + g) ^ (r2 & 7);
        bfr[mi][kk] = *(const bf16x8*)((const char*)Bs + r2 * 128 + cb * 16);
      }
#pragma unroll
    for (int mi = 0; mi < 4; ++mi)
#pragma unroll
      for (int nj = 0; nj < 4; ++nj)
#pragma unroll
        for (int kk = 0; kk < 2; ++kk)
          acc[mi][nj] = MFMA16(af[mi][kk], bfr[nj][kk], acc[mi][nj]);
  }

  if (EPI == 0) {
    // C rows m -> (b, n); cols e -> (part, h, hd). RoPE pair is lane^1.
    const int b = m0 >> 12;  // 4096 rows per batch, 128 | 4096 -> uniform
#pragma unroll
    for (int nj = 0; nj < 4; ++nj) {
      const int e = n0 + wc * 64 + nj * 16 + l15;
      const int part = e >> 10;           // wave-uniform (16-col tile)
      const int d = e & 1023;
      const int h = d >> 6, hd = d & 63;
#pragma unroll
      for (int mi = 0; mi < 4; ++mi) {
        if (part == 2) {
          // V transposed: [B, H, HD, N]; pack 4 consecutive n into 8B store
          const int nb = (m0 & 4095) + wr * 64 + mi * 16 + g * 4;
          uint2 pv;
          pv.x = (uint32_t)f2bf(acc[mi][nj][0]) |
                 ((uint32_t)f2bf(acc[mi][nj][1]) << 16);
          pv.y = (uint32_t)f2bf(acc[mi][nj][2]) |
                 ((uint32_t)f2bf(acc[mi][nj][3]) << 16);
          *(uint2*)(Vg + ((size_t)(b * Hc + h) * HDc + hd) * Nc + nb) = pv;
        } else {
          uint16_t* dst = (part == 0) ? Qb : Kb;
          const size_t base = ((size_t)(b * Hc + h) * Nc) * HDc + hd;
#pragma unroll
          for (int rg = 0; rg < 4; ++rg) {
            const int m = m0 + wr * 64 + mi * 16 + g * 4 + rg;
            const int n = m & (Nc - 1);
            const float val = acc[mi][nj][rg];
            const float partner = __shfl_xor(val, 1);
            const float x2 = (e & 1) ? partner : -partner;
            const float2 cs =
                *(const float2*)(rot + ((size_t)(b * Nc + n) * Dc + d) * 2);
            dst[base + (size_t)n * HDc] = f2bf(val * cs.x + x2 * cs.y);
          }
        }
      }
    }
  } else {
#pragma unroll
    for (int nj = 0; nj < 4; ++nj) {
      const int e = n0 + wc * 64 + nj * 16 + l15;
      const float bia = bias[e];
#pragma unroll
      for (int mi = 0; mi < 4; ++mi)
#pragma unroll
        for (int rg = 0; rg < 4; ++rg) {
          const int m = m0 + wr * 64 + mi * 16 + g * 4 + rg;
          Out[(size_t)m * Dc + e] = acc[mi][nj][rg] + bia;
        }
    }
  }
}

// ---------------------------------------------------------------------------
// Flash attention: Q [B,H,N,HD], K [B,H,N,HD], V^T [B,H,HD,N] -> O [B,N,D]
// block = 4 waves, QBLK=128 (32 q-rows/wave), KVBLK=64, online softmax.
// ---------------------------------------------------------------------------
__global__ __launch_bounds__(256, 2) void attn_fa(
    const uint16_t* __restrict__ Qb, const uint16_t* __restrict__ Kb,
    const uint16_t* __restrict__ Vg, uint16_t* __restrict__ Ob) {
  __shared__ __align__(16) uint16_t Ks[64 * 72];   // [kv][d] +8 pad
  __shared__ __align__(16) uint16_t Vt[64 * 72];   // [d][kv] +8 pad
  __shared__ __align__(16) uint16_t Pl[4][32 * 72];  // per-wave P
  const int tid = threadIdx.x;
  const int lane = tid & 63, wave = tid >> 6;
  const int l15 = lane & 15, g = lane >> 4;
  const int bh = blockIdx.y;
  const int q0 = blockIdx.x * 128;
  const size_t bhN = (size_t)bh * Nc;
  uint16_t* plw = &Pl[wave][0];

  // Q fragments register-resident for the whole block
  bf16x8 qf[2][2];
#pragma unroll
  for (int rf = 0; rf < 2; ++rf)
#pragma unroll
    for (int kk = 0; kk < 2; ++kk)
      qf[rf][kk] = *(const bf16x8*)(Qb + (bhN + q0 + wave * 32 + rf * 16 + l15) * HDc +
                                    kk * 32 + g * 8);

  const f32x4 fz = {0.f, 0.f, 0.f, 0.f};
  f32x4 O[2][4];
  float mrow[2][4], lrow[2][4];
#pragma unroll
  for (int rf = 0; rf < 2; ++rf) {
#pragma unroll
    for (int df = 0; df < 4; ++df) O[rf][df] = fz;
#pragma unroll
    for (int r4 = 0; r4 < 4; ++r4) { mrow[rf][r4] = -1e30f; lrow[rf][r4] = 0.f; }
  }

  for (int t = 0; t < Nc / 64; ++t) {
    const int kv0 = t * 64;
    __syncthreads();
#pragma unroll
    for (int i = 0; i < 2; ++i) {
      const int chunk = tid + i * 256;  // 0..511 : 64 rows x 8 chunks
      const int r = chunk >> 3, c = chunk & 7;
      *(bf16x8*)(&Ks[r * 72 + c * 8]) =
          *(const bf16x8*)(Kb + (bhN + kv0 + r) * HDc + c * 8);
      *(bf16x8*)(&Vt[r * 72 + c * 8]) =
          *(const bf16x8*)(Vg + ((size_t)bh * HDc + r) * Nc + kv0 + c * 8);
    }
    __syncthreads();

    // S = (Q @ K^T) * 0.125
    f32x4 S[2][4];
#pragma unroll
    for (int rf = 0; rf < 2; ++rf)
#pragma unroll
      for (int cf = 0; cf < 4; ++cf) {
        f32x4 s = fz;
#pragma unroll
        for (int kk = 0; kk < 2; ++kk) {
          bf16x8 kf = *(const bf16x8*)(&Ks[(cf * 16 + l15) * 72 + kk * 32 + g * 8]);
          s = MFMA16(qf[rf][kk], kf, s);
        }
        S[rf][cf] = s;
      }

    // online softmax (row = q). Row lives across the 16-lane (l15) group.
#pragma unroll
    for (int rf = 0; rf < 2; ++rf) {
#pragma unroll
      for (int r4 = 0; r4 < 4; ++r4) {
        float mx = -1e30f;
#pragma unroll
        for (int cf = 0; cf < 4; ++cf) {
          S[rf][cf][r4] *= 0.125f;
          mx = fmaxf(mx, S[rf][cf][r4]);
        }
#pragma unroll
        for (int dd = 1; dd < 16; dd <<= 1) mx = fmaxf(mx, __shfl_xor(mx, dd));
        const float mN = fmaxf(mrow[rf][r4], mx);
        const float corr = __expf(mrow[rf][r4] - mN);
        mrow[rf][r4] = mN;
        float rs = 0.f;
#pragma unroll
        for (int cf = 0; cf < 4; ++cf) {
          const float p = __expf(S[rf][cf][r4] - mN);
          S[rf][cf][r4] = p;
          rs += p;
        }
#pragma unroll
        for (int dd = 1; dd < 16; dd <<= 1) rs += __shfl_xor(rs, dd);
        lrow[rf][r4] = lrow[rf][r4] * corr + rs;
#pragma unroll
        for (int df = 0; df < 4; ++df) O[rf][df][r4] *= corr;
      }
    }

    // P -> per-wave LDS (C-layout scatter), then PV MFMA (A-layout reads)
#pragma unroll
    for (int rf = 0; rf < 2; ++rf)
#pragma unroll
      for (int cf = 0; cf < 4; ++cf)
#pragma unroll
        for (int r4 = 0; r4 < 4; ++r4)
          plw[(rf * 16 + g * 4 + r4) * 72 + cf * 16 + l15] = f2bf(S[rf][cf][r4]);

#pragma unroll
    for (int rf = 0; rf < 2; ++rf)
#pragma unroll
      for (int df = 0; df < 4; ++df)
#pragma unroll
        for (int kk = 0; kk < 2; ++kk) {
          bf16x8 pa = *(const bf16x8*)(&plw[(rf * 16 + l15) * 72 + kk * 32 + g * 8]);
          bf16x8 vb = *(const bf16x8*)(&Vt[(df * 16 + l15) * 72 + kk * 32 + g * 8]);
          O[rf][df] = MFMA16(pa, vb, O[rf][df]);
        }
  }

  // epilogue: O /= l, write [B, N, D] bf16
  const int b = bh >> 4, h = bh & 15;
#pragma unroll
  for (int rf = 0; rf < 2; ++rf) {
    float inv[4];
#pragma unroll
    for (int r4 = 0; r4 < 4; ++r4) inv[r4] = 1.f / lrow[rf][r4];
#pragma unroll
    for (int df = 0; df < 4; ++df)
#pragma unroll
      for (int r4 = 0; r4 < 4; ++r4) {
        const int n = q0 + wave * 32 + rf * 16 + g * 4 + r4;
        const int d = df * 16 + l15;
        Ob[((size_t)b * Nc + n) * Dc + h * HDc + d] = f2bf(O[rf][df][r4] * inv[r4]);
      }
  }
}

extern "C" void kernel_launch(void* const* d_in, const int* in_sizes, int n_in,
                              void* d_out, int out_size, void* d_ws, size_t ws_size,
                              hipStream_t stream) {
  const float* x = (const float*)d_in[0];      // [B,N,D] f32
  const float* rot = (const float*)d_in[1];    // [B,N,D,2] f32
  const float* Wqkv = (const float*)d_in[2];   // [3D,D] f32
  const float* Wout = (const float*)d_in[3];   // [D,D] f32
  const float* bout = (const float*)d_in[4];   // [D] f32
  float* out = (float*)d_out;                  // [B,N,D] f32

  uint16_t* ws = (uint16_t*)d_ws;
  const size_t XSZ = (size_t)Bc * Nc * Dc;        // 16,777,216 elems
  const size_t W1SZ = (size_t)3 * Dc * Dc;        //  3,145,728
  const size_t W2SZ = (size_t)Dc * Dc;            //  1,048,576
  uint16_t* xb = ws;               // bf16 x; ALIASED with At (safe: xb's last
  uint16_t* At = ws;               // read is gemm1; At first written by attn)
  uint16_t* Qb = ws + XSZ;
  uint16_t* Kb = ws + 2 * XSZ;
  uint16_t* Vg = ws + 3 * XSZ;     // transposed [B,H,HD,N]
  uint16_t* Wqb = ws + 4 * XSZ;
  uint16_t* Wob = ws + 4 * XSZ + W1SZ;
  // total: 4*XSZ + W1SZ + W2SZ = 71,303,168 elems = 142.6 MB

  dim3 blk(256);
  cvt_f32_bf16<<<dim3((XSZ / 8 + 255) / 256), blk, 0, stream>>>(x, xb, (int)XSZ);
  cvt_f32_bf16<<<dim3((W1SZ / 8 + 255) / 256), blk, 0, stream>>>(Wqkv, Wqb, (int)W1SZ);
  cvt_f32_bf16<<<dim3((W2SZ / 8 + 255) / 256), blk, 0, stream>>>(Wout, Wob, (int)W2SZ);

  gemm_bt<0><<<dim3((3 * Dc) / 128, (Bc * Nc) / 128), blk, 0, stream>>>(
      xb, Wqb, Dc, rot, Qb, Kb, Vg, nullptr, nullptr);
  attn_fa<<<dim3(Nc / 128, Bc * Hc), blk, 0, stream>>>(Qb, Kb, Vg, At);
  gemm_bt<1><<<dim3(Dc / 128, (Bc * Nc) / 128), blk, 0, stream>>>(
      At, Wob, Dc, nullptr, nullptr, nullptr, nullptr, bout, out);
}

// Round 3
// 809.697 us; speedup vs baseline: 1.3470x; 1.3470x over previous
//
#include <hip/hip_runtime.h>
#include <hip/hip_bf16.h>
#include <stdint.h>
#include <stddef.h>

typedef __attribute__((ext_vector_type(8))) __bf16 bf16x8;
typedef __attribute__((ext_vector_type(4))) float f32x4;

#define MFMA16(a, b, c) __builtin_amdgcn_mfma_f32_16x16x32_bf16((a), (b), (c), 0, 0, 0)

static constexpr int Bc = 4, Nc = 4096, Dc = 1024, Hc = 16, HDc = 64;

__device__ __forceinline__ uint16_t f2bf(float f) {
  __bf16 h = (__bf16)f;
  return __builtin_bit_cast(uint16_t, h);
}

// async global->LDS, 16B per lane. LDS dest must be wave-uniform-base + lane*16.
__device__ __forceinline__ void gload16(const void* g, void* l) {
  __builtin_amdgcn_global_load_lds(
      (__attribute__((address_space(1))) void*)(g),
      (__attribute__((address_space(3))) void*)(l), 16, 0, 0);
}

// ---------------------------------------------------------------------------
// f32 -> bf16 convert (vectorized, 8 elems/thread). n must be a multiple of 8.
// ---------------------------------------------------------------------------
__global__ __launch_bounds__(256) void cvt_f32_bf16(
    const float* __restrict__ src, uint16_t* __restrict__ dst, int n) {
  const int i = (blockIdx.x * 256 + threadIdx.x) * 8;
  if (i >= n) return;
  const float4 a = *(const float4*)(src + i);
  const float4 b = *(const float4*)(src + i + 4);
  union { uint16_t u[8]; uint4 v; } o;
  o.u[0] = f2bf(a.x); o.u[1] = f2bf(a.y); o.u[2] = f2bf(a.z); o.u[3] = f2bf(a.w);
  o.u[4] = f2bf(b.x); o.u[5] = f2bf(b.y); o.u[6] = f2bf(b.z); o.u[7] = f2bf(b.w);
  *(uint4*)(dst + i) = o.v;
}

// ---------------------------------------------------------------------------
// BT-GEMM: C[m, e] = sum_k A[m, k] * Bw[e, k].  128x128 tile, BK=64, 4 waves.
// EPI=0: QKV projection epilogue -> RoPE (f32 rot) -> Q/K [B,H,N,HD] bf16,
//        Q pre-scaled by 0.125 (exact in bf16), V transposed [B,H,HD,N] bf16
// EPI=1: bias add (f32) -> Out [M, 1024] f32
// ---------------------------------------------------------------------------
template <int EPI>
__global__ __launch_bounds__(256, 2) void gemm_bt(
    const uint16_t* __restrict__ A, const uint16_t* __restrict__ Bw, int K,
    const float* __restrict__ rot, uint16_t* __restrict__ Qb,
    uint16_t* __restrict__ Kb, uint16_t* __restrict__ Vg,
    const float* __restrict__ bias, float* __restrict__ Out) {
  __shared__ __align__(16) uint16_t As[128 * 64];
  __shared__ __align__(16) uint16_t Bs[128 * 64];
  const int tid = threadIdx.x;
  const int lane = tid & 63, wave = tid >> 6;
  const int l15 = lane & 15, g = lane >> 4;
  const int wr = wave >> 1, wc = wave & 1;
  const int m0 = blockIdx.y * 128;
  const int n0 = blockIdx.x * 128;

  f32x4 acc[4][4];
  const f32x4 fz = {0.f, 0.f, 0.f, 0.f};
#pragma unroll
  for (int i = 0; i < 4; ++i)
#pragma unroll
    for (int j = 0; j < 4; ++j) acc[i][j] = fz;

  for (int kt = 0; kt < K; kt += 64) {
    __syncthreads();  // previous iter's LDS reads done before overwrite
#pragma unroll
    for (int i = 0; i < 4; ++i) {
      const int chunk = tid + i * 256;  // 0..1023 : 128 rows x 8 chunks(16B)
      const int r = chunk >> 3, c = chunk & 7;
      const int cs = c ^ (r & 7);  // pre-swizzled source (linear LDS dest)
      gload16(A + (size_t)(m0 + r) * K + kt + cs * 8, &As[chunk * 8]);
      gload16(Bw + (size_t)(n0 + r) * K + kt + cs * 8, &Bs[chunk * 8]);
    }
    __syncthreads();  // implies vmcnt(0): staged data visible

    bf16x8 af[4][2], bfr[4][2];
#pragma unroll
    for (int mi = 0; mi < 4; ++mi)
#pragma unroll
      for (int kk = 0; kk < 2; ++kk) {
        const int r = wr * 64 + mi * 16 + l15;
        const int ca = (kk * 4 + g) ^ (r & 7);
        af[mi][kk] = *(const bf16x8*)((const char*)As + r * 128 + ca * 16);
        const int r2 = wc * 64 + mi * 16 + l15;
        const int cb = (kk * 4 + g) ^ (r2 & 7);
        bfr[mi][kk] = *(const bf16x8*)((const char*)Bs + r2 * 128 + cb * 16);
      }
#pragma unroll
    for (int mi = 0; mi < 4; ++mi)
#pragma unroll
      for (int nj = 0; nj < 4; ++nj)
#pragma unroll
        for (int kk = 0; kk < 2; ++kk)
          acc[mi][nj] = MFMA16(af[mi][kk], bfr[nj][kk], acc[mi][nj]);
  }

  if (EPI == 0) {
    // C rows m -> (b, n); cols e -> (part, h, hd). RoPE pair is lane^1.
    const int b = m0 >> 12;  // 4096 rows per batch, 128 | 4096 -> uniform
#pragma unroll
    for (int nj = 0; nj < 4; ++nj) {
      const int e = n0 + wc * 64 + nj * 16 + l15;
      const int part = e >> 10;           // wave-uniform (16-col tile)
      const int d = e & 1023;
      const int h = d >> 6, hd = d & 63;
      const float sc = (part == 0) ? 0.125f : 1.0f;  // fold softmax scale into Q
#pragma unroll
      for (int mi = 0; mi < 4; ++mi) {
        if (part == 2) {
          // V transposed: [B, H, HD, N]; pack 4 consecutive n into 8B store
          const int nb = (m0 & 4095) + wr * 64 + mi * 16 + g * 4;
          uint2 pv;
          pv.x = (uint32_t)f2bf(acc[mi][nj][0]) |
                 ((uint32_t)f2bf(acc[mi][nj][1]) << 16);
          pv.y = (uint32_t)f2bf(acc[mi][nj][2]) |
                 ((uint32_t)f2bf(acc[mi][nj][3]) << 16);
          *(uint2*)(Vg + ((size_t)(b * Hc + h) * HDc + hd) * Nc + nb) = pv;
        } else {
          uint16_t* dst = (part == 0) ? Qb : Kb;
          const size_t base = ((size_t)(b * Hc + h) * Nc) * HDc + hd;
#pragma unroll
          for (int rg = 0; rg < 4; ++rg) {
            const int m = m0 + wr * 64 + mi * 16 + g * 4 + rg;
            const int n = m & (Nc - 1);
            const float val = acc[mi][nj][rg];
            const float partner = __shfl_xor(val, 1);
            const float x2 = (e & 1) ? partner : -partner;
            const float2 cs =
                *(const float2*)(rot + ((size_t)(b * Nc + n) * Dc + d) * 2);
            dst[base + (size_t)n * HDc] = f2bf((val * cs.x + x2 * cs.y) * sc);
          }
        }
      }
    }
  } else {
#pragma unroll
    for (int nj = 0; nj < 4; ++nj) {
      const int e = n0 + wc * 64 + nj * 16 + l15;
      const float bia = bias[e];
#pragma unroll
      for (int mi = 0; mi < 4; ++mi)
#pragma unroll
        for (int rg = 0; rg < 4; ++rg) {
          const int m = m0 + wr * 64 + mi * 16 + g * 4 + rg;
          Out[(size_t)m * Dc + e] = acc[mi][nj][rg] + bia;
        }
    }
  }
}

// ---------------------------------------------------------------------------
// Flash attention, swapped-QK variant: St = mfma(K, Q) puts a full q-row's
// S-values in one lane (col=lane&15 = q, row = g*4+r4 = kv) -> softmax is
// 15 in-lane ops + 2 shfl_xor instead of per-row 16-lane trees.
// Q [B,H,N,HD] (pre-scaled 0.125), K [B,H,N,HD], V^T [B,H,HD,N] -> At bf16.
// 4 waves, QBLK=128 (32 q/wave), KVBLK=64. K/V staged via global_load_lds
// with pre-swizzled source columns (zero-conflict reads, gemm-validated).
// ---------------------------------------------------------------------------
__global__ __launch_bounds__(256, 4) void attn_fa(
    const uint16_t* __restrict__ Qb, const uint16_t* __restrict__ Kb,
    const uint16_t* __restrict__ Vg, uint16_t* __restrict__ Ob) {
  __shared__ __align__(16) uint16_t Ks[64 * 64];     // [kv][d], XOR-chunk swizzled
  __shared__ __align__(16) uint16_t Vt[64 * 64];     // [d][kv], XOR-chunk swizzled
  __shared__ __align__(16) uint16_t Pl[4][16 * 72];  // per-wave P^T [q=16][kv=64] +pad
  const int tid = threadIdx.x;
  const int lane = tid & 63, wave = tid >> 6;
  const int l15 = lane & 15, g = lane >> 4;
  const int bh = blockIdx.y;
  const int q0 = blockIdx.x * 128;
  const size_t bhN = (size_t)bh * Nc;
  uint16_t* plw = &Pl[wave][0];

  // Q fragments register-resident for the whole block (B-operand layout)
  bf16x8 qf[2][2];
#pragma unroll
  for (int rf = 0; rf < 2; ++rf)
#pragma unroll
    for (int kk = 0; kk < 2; ++kk)
      qf[rf][kk] = *(const bf16x8*)(Qb + (bhN + q0 + wave * 32 + rf * 16 + l15) * HDc +
                                    kk * 32 + g * 8);

  const f32x4 fz = {0.f, 0.f, 0.f, 0.f};
  f32x4 O[2][4];
  float mrow[2] = {-1e30f, -1e30f}, lrow[2] = {0.f, 0.f};
#pragma unroll
  for (int rf = 0; rf < 2; ++rf)
#pragma unroll
    for (int df = 0; df < 4; ++df) O[rf][df] = fz;

  for (int t = 0; t < Nc / 64; ++t) {
    const int kv0 = t * 64;
    __syncthreads();  // prev iter's Ks/Vt reads done
#pragma unroll
    for (int i = 0; i < 2; ++i) {
      const int ch = tid + i * 256;  // 0..511 : 64 rows x 8 chunks(16B)
      const int r = ch >> 3, c = ch & 7;
      const int cs = c ^ (r & 7);  // pre-swizzled source, linear LDS dest
      gload16(Kb + (bhN + kv0 + r) * HDc + cs * 8, &Ks[ch * 8]);
      gload16(Vg + ((size_t)bh * HDc + r) * Nc + kv0 + cs * 8, &Vt[ch * 8]);
    }
    __syncthreads();  // staged data visible

    // St[rf][cf]: S^T tile. lane(g,l15) reg r4 = S[q=l15(+rf*16)][kv=cf*16+g*4+r4]
    f32x4 St[2][4];
#pragma unroll
    for (int rf = 0; rf < 2; ++rf)
#pragma unroll
      for (int cf = 0; cf < 4; ++cf) St[rf][cf] = fz;
#pragma unroll
    for (int cf = 0; cf < 4; ++cf)
#pragma unroll
      for (int kk = 0; kk < 2; ++kk) {
        const int row = cf * 16 + l15;
        bf16x8 kf = *(const bf16x8*)(&Ks[row * 64 + (((kk * 4 + g) ^ (l15 & 7)) * 8)]);
        St[0][cf] = MFMA16(kf, qf[0][kk], St[0][cf]);
        St[1][cf] = MFMA16(kf, qf[1][kk], St[1][cf]);
      }

#pragma unroll
    for (int rf = 0; rf < 2; ++rf) {
      // row max: 16 in-lane values + combine 4 g-groups
      float mx = St[rf][0][0];
#pragma unroll
      for (int cf = 0; cf < 4; ++cf)
#pragma unroll
        for (int r4 = 0; r4 < 4; ++r4) mx = fmaxf(mx, St[rf][cf][r4]);
      mx = fmaxf(mx, __shfl_xor(mx, 16));
      mx = fmaxf(mx, __shfl_xor(mx, 32));
      const float mN = fmaxf(mrow[rf], mx);
      const float corr = __expf(mrow[rf] - mN);
      mrow[rf] = mN;
      float rs = 0.f;
#pragma unroll
      for (int cf = 0; cf < 4; ++cf)
#pragma unroll
        for (int r4 = 0; r4 < 4; ++r4) {
          const float p = __expf(St[rf][cf][r4] - mN);
          St[rf][cf][r4] = p;
          rs += p;
        }
      rs += __shfl_xor(rs, 16);
      rs += __shfl_xor(rs, 32);
      lrow[rf] = lrow[rf] * corr + rs;

      // O-rescale: O rows are q = g*4+r4; corr lives on lane l15 = q
      float cb[4];
#pragma unroll
      for (int r4 = 0; r4 < 4; ++r4) cb[r4] = __shfl(corr, g * 4 + r4, 16);
#pragma unroll
      for (int df = 0; df < 4; ++df)
#pragma unroll
        for (int r4 = 0; r4 < 4; ++r4) O[rf][df][r4] *= cb[r4];

      // P pack: consecutive r4 = consecutive kv -> one b64 write per cf
#pragma unroll
      for (int cf = 0; cf < 4; ++cf) {
        uint2 pv;
        pv.x = (uint32_t)f2bf(St[rf][cf][0]) | ((uint32_t)f2bf(St[rf][cf][1]) << 16);
        pv.y = (uint32_t)f2bf(St[rf][cf][2]) | ((uint32_t)f2bf(St[rf][cf][3]) << 16);
        *(uint2*)(plw + l15 * 72 + cf * 16 + g * 4) = pv;
      }

      // PV: pa = P A-fragment (lane l15 = q, 8 contiguous kv per lane)
      bf16x8 pa0 = *(const bf16x8*)(plw + l15 * 72 + g * 8);
      bf16x8 pa1 = *(const bf16x8*)(plw + l15 * 72 + 32 + g * 8);
#pragma unroll
      for (int df = 0; df < 4; ++df) {
        const int row = df * 16 + l15;
        bf16x8 vb0 = *(const bf16x8*)(&Vt[row * 64 + ((g ^ (l15 & 7)) * 8)]);
        bf16x8 vb1 = *(const bf16x8*)(&Vt[row * 64 + (((4 + g) ^ (l15 & 7)) * 8)]);
        O[rf][df] = MFMA16(pa0, vb0, O[rf][df]);
        O[rf][df] = MFMA16(pa1, vb1, O[rf][df]);
      }
    }
  }

  // epilogue: O /= l (broadcast by q), write [B, N, D] bf16
  const int b = bh >> 4, h = bh & 15;
#pragma unroll
  for (int rf = 0; rf < 2; ++rf) {
    float inv[4];
#pragma unroll
    for (int r4 = 0; r4 < 4; ++r4) inv[r4] = 1.f / __shfl(lrow[rf], g * 4 + r4, 16);
#pragma unroll
    for (int df = 0; df < 4; ++df)
#pragma unroll
      for (int r4 = 0; r4 < 4; ++r4) {
        const int n = q0 + wave * 32 + rf * 16 + g * 4 + r4;
        const int d = df * 16 + l15;
        Ob[((size_t)b * Nc + n) * Dc + h * HDc + d] = f2bf(O[rf][df][r4] * inv[r4]);
      }
  }
}

extern "C" void kernel_launch(void* const* d_in, const int* in_sizes, int n_in,
                              void* d_out, int out_size, void* d_ws, size_t ws_size,
                              hipStream_t stream) {
  const float* x = (const float*)d_in[0];      // [B,N,D] f32
  const float* rot = (const float*)d_in[1];    // [B,N,D,2] f32
  const float* Wqkv = (const float*)d_in[2];   // [3D,D] f32
  const float* Wout = (const float*)d_in[3];   // [D,D] f32
  const float* bout = (const float*)d_in[4];   // [D] f32
  float* out = (float*)d_out;                  // [B,N,D] f32

  uint16_t* ws = (uint16_t*)d_ws;
  const size_t XSZ = (size_t)Bc * Nc * Dc;        // 16,777,216 elems
  const size_t W1SZ = (size_t)3 * Dc * Dc;        //  3,145,728
  const size_t W2SZ = (size_t)Dc * Dc;            //  1,048,576
  uint16_t* xb = ws;               // bf16 x; ALIASED with At (safe: xb's last
  uint16_t* At = ws;               // read is gemm1; At first written by attn)
  uint16_t* Qb = ws + XSZ;
  uint16_t* Kb = ws + 2 * XSZ;
  uint16_t* Vg = ws + 3 * XSZ;     // transposed [B,H,HD,N]
  uint16_t* Wqb = ws + 4 * XSZ;
  uint16_t* Wob = ws + 4 * XSZ + W1SZ;
  // total: 4*XSZ + W1SZ + W2SZ = 71,303,168 elems = 142.6 MB

  dim3 blk(256);
  cvt_f32_bf16<<<dim3((XSZ / 8 + 255) / 256), blk, 0, stream>>>(x, xb, (int)XSZ);
  cvt_f32_bf16<<<dim3((W1SZ / 8 + 255) / 256), blk, 0, stream>>>(Wqkv, Wqb, (int)W1SZ);
  cvt_f32_bf16<<<dim3((W2SZ / 8 + 255) / 256), blk, 0, stream>>>(Wout, Wob, (int)W2SZ);

  gemm_bt<0><<<dim3((3 * Dc) / 128, (Bc * Nc) / 128), blk, 0, stream>>>(
      xb, Wqb, Dc, rot, Qb, Kb, Vg, nullptr, nullptr);
  attn_fa<<<dim3(Nc / 128, Bc * Hc), blk, 0, stream>>>(Qb, Kb, Vg, At);
  gemm_bt<1><<<dim3(Dc / 128, (Bc * Nc) / 128), blk, 0, stream>>>(
      At, Wob, Dc, nullptr, nullptr, nullptr, nullptr, bout, out);
}

// Round 4
// 709.527 us; speedup vs baseline: 1.5372x; 1.1412x over previous
//
#include <hip/hip_runtime.h>
#include <hip/hip_bf16.h>
#include <stdint.h>
#include <stddef.h>

typedef __attribute__((ext_vector_type(8))) __bf16 bf16x8;
typedef __attribute__((ext_vector_type(4))) float f32x4;

#define MFMA16(a, b, c) __builtin_amdgcn_mfma_f32_16x16x32_bf16((a), (b), (c), 0, 0, 0)

static constexpr int Bc = 4, Nc = 4096, Dc = 1024, Hc = 16, HDc = 64;

__device__ __forceinline__ uint16_t f2bf(float f) {
  __bf16 h = (__bf16)f;
  return __builtin_bit_cast(uint16_t, h);
}

// async global->LDS, 16B per lane. LDS dest must be wave-uniform base + lane*16.
__device__ __forceinline__ void gload16(const void* g, void* l) {
  __builtin_amdgcn_global_load_lds(
      (__attribute__((address_space(1))) void*)(g),
      (__attribute__((address_space(3))) void*)(l), 16, 0, 0);
}

// ---------------------------------------------------------------------------
// f32 -> bf16 convert (vectorized, 8 elems/thread). n must be a multiple of 8.
// ---------------------------------------------------------------------------
__global__ __launch_bounds__(256) void cvt_f32_bf16(
    const float* __restrict__ src, uint16_t* __restrict__ dst, int n) {
  const int i = (blockIdx.x * 256 + threadIdx.x) * 8;
  if (i >= n) return;
  const float4 a = *(const float4*)(src + i);
  const float4 b = *(const float4*)(src + i + 4);
  union { uint16_t u[8]; uint4 v; } o;
  o.u[0] = f2bf(a.x); o.u[1] = f2bf(a.y); o.u[2] = f2bf(a.z); o.u[3] = f2bf(a.w);
  o.u[4] = f2bf(b.x); o.u[5] = f2bf(b.y); o.u[6] = f2bf(b.z); o.u[7] = f2bf(b.w);
  *(uint4*)(dst + i) = o.v;
}

// ---------------------------------------------------------------------------
// BT-GEMM: C[m, e] = sum_k A[m, k] * Bw[e, k].  128x128 tile, BK=64, 4 waves.
// EPI=0: QKV projection epilogue -> RoPE (f32 rot) -> Q/K [B,H,N,HD] bf16,
//        Q pre-scaled by 0.125 (exact in bf16), V transposed [B,H,HD,N] bf16
// EPI=1: bias add (f32) -> Out [M, 1024] f32
// ---------------------------------------------------------------------------
template <int EPI>
__global__ __launch_bounds__(256, 2) void gemm_bt(
    const uint16_t* __restrict__ A, const uint16_t* __restrict__ Bw, int K,
    const float* __restrict__ rot, uint16_t* __restrict__ Qb,
    uint16_t* __restrict__ Kb, uint16_t* __restrict__ Vg,
    const float* __restrict__ bias, float* __restrict__ Out) {
  __shared__ __align__(16) uint16_t As[128 * 64];
  __shared__ __align__(16) uint16_t Bs[128 * 64];
  const int tid = threadIdx.x;
  const int lane = tid & 63, wave = tid >> 6;
  const int l15 = lane & 15, g = lane >> 4;
  const int wr = wave >> 1, wc = wave & 1;
  const int m0 = blockIdx.y * 128;
  const int n0 = blockIdx.x * 128;

  f32x4 acc[4][4];
  const f32x4 fz = {0.f, 0.f, 0.f, 0.f};
#pragma unroll
  for (int i = 0; i < 4; ++i)
#pragma unroll
    for (int j = 0; j < 4; ++j) acc[i][j] = fz;

  for (int kt = 0; kt < K; kt += 64) {
    __syncthreads();  // previous iter's LDS reads done before overwrite
#pragma unroll
    for (int i = 0; i < 4; ++i) {
      const int chunk = tid + i * 256;  // 0..1023 : 128 rows x 8 chunks(16B)
      const int r = chunk >> 3, c = chunk & 7;
      const int cs = c ^ (r & 7);  // pre-swizzled source (linear LDS dest)
      gload16(A + (size_t)(m0 + r) * K + kt + cs * 8, &As[chunk * 8]);
      gload16(Bw + (size_t)(n0 + r) * K + kt + cs * 8, &Bs[chunk * 8]);
    }
    __syncthreads();  // implies vmcnt(0): staged data visible

    bf16x8 af[4][2], bfr[4][2];
#pragma unroll
    for (int mi = 0; mi < 4; ++mi)
#pragma unroll
      for (int kk = 0; kk < 2; ++kk) {
        const int r = wr * 64 + mi * 16 + l15;
        const int ca = (kk * 4 + g) ^ (r & 7);
        af[mi][kk] = *(const bf16x8*)((const char*)As + r * 128 + ca * 16);
        const int r2 = wc * 64 + mi * 16 + l15;
        const int cb = (kk * 4 + g) ^ (r2 & 7);
        bfr[mi][kk] = *(const bf16x8*)((const char*)Bs + r2 * 128 + cb * 16);
      }
#pragma unroll
    for (int mi = 0; mi < 4; ++mi)
#pragma unroll
      for (int nj = 0; nj < 4; ++nj)
#pragma unroll
        for (int kk = 0; kk < 2; ++kk)
          acc[mi][nj] = MFMA16(af[mi][kk], bfr[nj][kk], acc[mi][nj]);
  }

  if (EPI == 0) {
    // C rows m -> (b, n); cols e -> (part, h, hd). RoPE pair is lane^1.
    const int b = m0 >> 12;  // 4096 rows per batch, 128 | 4096 -> uniform
#pragma unroll
    for (int nj = 0; nj < 4; ++nj) {
      const int e = n0 + wc * 64 + nj * 16 + l15;
      const int part = e >> 10;           // wave-uniform (16-col tile)
      const int d = e & 1023;
      const int h = d >> 6, hd = d & 63;
      const float sc = (part == 0) ? 0.125f : 1.0f;  // fold softmax scale into Q
#pragma unroll
      for (int mi = 0; mi < 4; ++mi) {
        if (part == 2) {
          // V transposed: [B, H, HD, N]; pack 4 consecutive n into 8B store
          const int nb = (m0 & 4095) + wr * 64 + mi * 16 + g * 4;
          uint2 pv;
          pv.x = (uint32_t)f2bf(acc[mi][nj][0]) |
                 ((uint32_t)f2bf(acc[mi][nj][1]) << 16);
          pv.y = (uint32_t)f2bf(acc[mi][nj][2]) |
                 ((uint32_t)f2bf(acc[mi][nj][3]) << 16);
          *(uint2*)(Vg + ((size_t)(b * Hc + h) * HDc + hd) * Nc + nb) = pv;
        } else {
          uint16_t* dst = (part == 0) ? Qb : Kb;
          const size_t base = ((size_t)(b * Hc + h) * Nc) * HDc + hd;
#pragma unroll
          for (int rg = 0; rg < 4; ++rg) {
            const int m = m0 + wr * 64 + mi * 16 + g * 4 + rg;
            const int n = m & (Nc - 1);
            const float val = acc[mi][nj][rg];
            const float partner = __shfl_xor(val, 1);
            const float x2 = (e & 1) ? partner : -partner;
            const float2 cs =
                *(const float2*)(rot + ((size_t)(b * Nc + n) * Dc + d) * 2);
            dst[base + (size_t)n * HDc] = f2bf((val * cs.x + x2 * cs.y) * sc);
          }
        }
      }
    }
  } else {
#pragma unroll
    for (int nj = 0; nj < 4; ++nj) {
      const int e = n0 + wc * 64 + nj * 16 + l15;
      const float bia = bias[e];
#pragma unroll
      for (int mi = 0; mi < 4; ++mi)
#pragma unroll
        for (int rg = 0; rg < 4; ++rg) {
          const int m = m0 + wr * 64 + mi * 16 + g * 4 + rg;
          Out[(size_t)m * Dc + e] = acc[mi][nj][rg] + bia;
        }
    }
  }
}

// ---------------------------------------------------------------------------
// Flash attention, swapped-QK + swapped-PV + prefetch double-buffer.
//  St = mfma(K, Q): lane l15 = q, regs = kv  -> in-lane softmax.
//  Ot = mfma(V, P): lane l15 = q, regs = d   -> per-lane rescale/epilogue,
//    no cross-lane broadcasts at all.
//  K/V LDS double-buffered; stage(t+1) issued right after the single barrier
//  so global_load_lds flies under compute (T3 2-phase). Defer-rescale (T13).
// ---------------------------------------------------------------------------
__global__ __launch_bounds__(256, 3) void attn_fa(
    const uint16_t* __restrict__ Qb, const uint16_t* __restrict__ Kb,
    const uint16_t* __restrict__ Vg, uint16_t* __restrict__ Ob) {
  __shared__ __align__(16) uint16_t Ks[2][64 * 64];  // [kv][d], chunk-swizzled
  __shared__ __align__(16) uint16_t Vt[2][64 * 64];  // [d][kv], chunk-swizzled
  __shared__ __align__(16) uint16_t Pl[4][16 * 72];  // per-wave P^T [q=16][kv=64]
  const int tid = threadIdx.x;
  const int lane = tid & 63, wave = tid >> 6;
  const int l15 = lane & 15, g = lane >> 4;
  const int bh = blockIdx.y;
  const int q0 = blockIdx.x * 128;
  const size_t bhN = (size_t)bh * Nc;
  uint16_t* plw = &Pl[wave][0];

  // Q fragments register-resident for the whole block (B-operand layout)
  bf16x8 qf[2][2];
#pragma unroll
  for (int rf = 0; rf < 2; ++rf)
#pragma unroll
    for (int kk = 0; kk < 2; ++kk)
      qf[rf][kk] = *(const bf16x8*)(Qb + (bhN + q0 + wave * 32 + rf * 16 + l15) * HDc +
                                    kk * 32 + g * 8);

  const f32x4 fz = {0.f, 0.f, 0.f, 0.f};
  f32x4 O[2][4];
  float mrow[2] = {-1e30f, -1e30f}, lrow[2] = {0.f, 0.f};
#pragma unroll
  for (int rf = 0; rf < 2; ++rf)
#pragma unroll
    for (int df = 0; df < 4; ++df) O[rf][df] = fz;

  // stage K/V tile t into LDS buffer `buf` (linear dest, pre-swizzled source)
  auto STAGE = [&](int buf, int t) {
    const int kv0 = t * 64;
#pragma unroll
    for (int i = 0; i < 2; ++i) {
      const int ch = tid + i * 256;  // 0..511 : 64 rows x 8 chunks(16B)
      const int r = ch >> 3, c = ch & 7;
      const int cs = c ^ (r & 7);
      gload16(Kb + (bhN + kv0 + r) * HDc + cs * 8, &Ks[buf][ch * 8]);
      gload16(Vg + ((size_t)bh * HDc + r) * Nc + kv0 + cs * 8, &Vt[buf][ch * 8]);
    }
  };

  STAGE(0, 0);
  int cur = 0;
  for (int t = 0; t < Nc / 64; ++t) {
    __syncthreads();  // drains vmcnt: tile t visible; prev iter's reads closed
    if (t < Nc / 64 - 1) STAGE(cur ^ 1, t + 1);  // flies under compute below

    const uint16_t* ks = &Ks[cur][0];
    const uint16_t* vt = &Vt[cur][0];

    // St[rf][cf]: lane(g,l15) reg r4 = S[q=l15+rf*16][kv=cf*16+g*4+r4]
    f32x4 St[2][4];
#pragma unroll
    for (int rf = 0; rf < 2; ++rf)
#pragma unroll
      for (int cf = 0; cf < 4; ++cf) St[rf][cf] = fz;
    __builtin_amdgcn_s_setprio(1);
#pragma unroll
    for (int cf = 0; cf < 4; ++cf)
#pragma unroll
      for (int kk = 0; kk < 2; ++kk) {
        const int row = cf * 16 + l15;
        bf16x8 kf = *(const bf16x8*)(&ks[row * 64 + (((kk * 4 + g) ^ (l15 & 7)) * 8)]);
        St[0][cf] = MFMA16(kf, qf[0][kk], St[0][cf]);
        St[1][cf] = MFMA16(kf, qf[1][kk], St[1][cf]);
      }
    __builtin_amdgcn_s_setprio(0);

    // V fragments (A-operand: row = d = df*16+l15), hoisted out of rf loop
    bf16x8 vb[4][2];
#pragma unroll
    for (int df = 0; df < 4; ++df) {
      const int row = df * 16 + l15;
      vb[df][0] = *(const bf16x8*)(&vt[row * 64 + ((g ^ (l15 & 7)) * 8)]);
      vb[df][1] = *(const bf16x8*)(&vt[row * 64 + (((4 + g) ^ (l15 & 7)) * 8)]);
    }

#pragma unroll
    for (int rf = 0; rf < 2; ++rf) {
      // tile max for this q-row (in-lane 16 + combine 4 g-groups)
      float pm = St[rf][0][0];
#pragma unroll
      for (int cf = 0; cf < 4; ++cf)
#pragma unroll
        for (int r4 = 0; r4 < 4; ++r4) pm = fmaxf(pm, St[rf][cf][r4]);
      pm = fmaxf(pm, __shfl_xor(pm, 16));
      pm = fmaxf(pm, __shfl_xor(pm, 32));

      // defer-rescale: only pay the O-pass when max grew by > 8
      if (__any(pm > mrow[rf] + 8.0f)) {
        const float mN = fmaxf(mrow[rf], pm);
        const float corr = __expf(mrow[rf] - mN);
        mrow[rf] = mN;
        lrow[rf] *= corr;
#pragma unroll
        for (int df = 0; df < 4; ++df)
#pragma unroll
          for (int r4 = 0; r4 < 4; ++r4) O[rf][df][r4] *= corr;
      }
      const float mN = mrow[rf];

      float rs = 0.f;
#pragma unroll
      for (int cf = 0; cf < 4; ++cf)
#pragma unroll
        for (int r4 = 0; r4 < 4; ++r4) {
          const float p = __expf(St[rf][cf][r4] - mN);
          St[rf][cf][r4] = p;
          rs += p;
        }
      rs += __shfl_xor(rs, 16);
      rs += __shfl_xor(rs, 32);
      lrow[rf] += rs;

      // P pack: consecutive r4 = consecutive kv -> one b64 write per cf
#pragma unroll
      for (int cf = 0; cf < 4; ++cf) {
        uint2 pv;
        pv.x = (uint32_t)f2bf(St[rf][cf][0]) | ((uint32_t)f2bf(St[rf][cf][1]) << 16);
        pv.y = (uint32_t)f2bf(St[rf][cf][2]) | ((uint32_t)f2bf(St[rf][cf][3]) << 16);
        *(uint2*)(plw + l15 * 72 + cf * 16 + g * 4) = pv;
      }

      // PV with swapped args: Ot[col=q=l15][row=d] = mfma(V-frag, P-frag)
      bf16x8 pa0 = *(const bf16x8*)(plw + l15 * 72 + g * 8);
      bf16x8 pa1 = *(const bf16x8*)(plw + l15 * 72 + 32 + g * 8);
      __builtin_amdgcn_s_setprio(1);
#pragma unroll
      for (int df = 0; df < 4; ++df) {
        O[rf][df] = MFMA16(vb[df][0], pa0, O[rf][df]);
        O[rf][df] = MFMA16(vb[df][1], pa1, O[rf][df]);
      }
      __builtin_amdgcn_s_setprio(0);
    }
    cur ^= 1;
  }

  // epilogue: per-lane normalize (q = l15), packed 8B stores
  const int b = bh >> 4, h = bh & 15;
#pragma unroll
  for (int rf = 0; rf < 2; ++rf) {
    const float inv = 1.f / lrow[rf];
    const int n = q0 + wave * 32 + rf * 16 + l15;
    uint16_t* orow = Ob + ((size_t)b * Nc + n) * Dc + h * HDc;
#pragma unroll
    for (int df = 0; df < 4; ++df) {
      uint2 pv;
      pv.x = (uint32_t)f2bf(O[rf][df][0] * inv) |
             ((uint32_t)f2bf(O[rf][df][1] * inv) << 16);
      pv.y = (uint32_t)f2bf(O[rf][df][2] * inv) |
             ((uint32_t)f2bf(O[rf][df][3] * inv) << 16);
      *(uint2*)(orow + df * 16 + g * 4) = pv;
    }
  }
}

extern "C" void kernel_launch(void* const* d_in, const int* in_sizes, int n_in,
                              void* d_out, int out_size, void* d_ws, size_t ws_size,
                              hipStream_t stream) {
  const float* x = (const float*)d_in[0];      // [B,N,D] f32
  const float* rot = (const float*)d_in[1];    // [B,N,D,2] f32
  const float* Wqkv = (const float*)d_in[2];   // [3D,D] f32
  const float* Wout = (const float*)d_in[3];   // [D,D] f32
  const float* bout = (const float*)d_in[4];   // [D] f32
  float* out = (float*)d_out;                  // [B,N,D] f32

  uint16_t* ws = (uint16_t*)d_ws;
  const size_t XSZ = (size_t)Bc * Nc * Dc;        // 16,777,216 elems
  const size_t W1SZ = (size_t)3 * Dc * Dc;        //  3,145,728
  const size_t W2SZ = (size_t)Dc * Dc;            //  1,048,576
  uint16_t* xb = ws;               // bf16 x; ALIASED with At (safe: xb's last
  uint16_t* At = ws;               // read is gemm1; At first written by attn)
  uint16_t* Qb = ws + XSZ;
  uint16_t* Kb = ws + 2 * XSZ;
  uint16_t* Vg = ws + 3 * XSZ;     // transposed [B,H,HD,N]
  uint16_t* Wqb = ws + 4 * XSZ;
  uint16_t* Wob = ws + 4 * XSZ + W1SZ;
  // total: 4*XSZ + W1SZ + W2SZ = 71,303,168 elems = 142.6 MB

  dim3 blk(256);
  cvt_f32_bf16<<<dim3((XSZ / 8 + 255) / 256), blk, 0, stream>>>(x, xb, (int)XSZ);
  cvt_f32_bf16<<<dim3((W1SZ / 8 + 255) / 256), blk, 0, stream>>>(Wqkv, Wqb, (int)W1SZ);
  cvt_f32_bf16<<<dim3((W2SZ / 8 + 255) / 256), blk, 0, stream>>>(Wout, Wob, (int)W2SZ);

  gemm_bt<0><<<dim3((3 * Dc) / 128, (Bc * Nc) / 128), blk, 0, stream>>>(
      xb, Wqb, Dc, rot, Qb, Kb, Vg, nullptr, nullptr);
  attn_fa<<<dim3(Nc / 128, Bc * Hc), blk, 0, stream>>>(Qb, Kb, Vg, At);
  gemm_bt<1><<<dim3(Dc / 128, (Bc * Nc) / 128), blk, 0, stream>>>(
      At, Wob, Dc, nullptr, nullptr, nullptr, nullptr, bout, out);
}